// Round 3
// baseline (991.879 us; speedup 1.0000x reference)
//
#include <hip/hip_runtime.h>
#include <math.h>

// B=8, N=1024, D=256, H=4, hd=64, k=153
// K1: f64-accurate projections stored f64 in ws (32 MB).
// K2: f64 adj GEMM (src via readlane broadcast, tgt via swizzled LDS),
//     exact top-k via linear-key radix + f64 tie fallback, f32 gelu output.

#define KSEL 153u

__device__ __forceinline__ float gelu_f32(float x) {
    return 0.5f * x * (1.0f + erff(x * 0.70710678118654752f));
}

// monotonic f64->u64 key: larger double => larger key
__device__ __forceinline__ unsigned long long d2key(double v) {
    unsigned long long u = (unsigned long long)__double_as_longlong(v);
    return (u >> 63) ? ~u : (u | 0x8000000000000000ull);
}

// linear 32-bit monotone key: spreads radix digits uniformly over value range.
// |adj| < 64 guaranteed (sigma=8, 4M samples => max ~45).
__device__ __forceinline__ unsigned lkey(double v) {
    double q = (v + 64.0) * 33554432.0;  // 2^25
    q = fmax(q, 0.0);
    q = fmin(q, 4294967295.0);
    return (unsigned)q;
}

// ---------------- K1: projections, f64 accumulate, f64 store ----------------
// grid (128, 8): bx = 64-row m-tile of x[8192,256]; by<4 -> W_src cols (by&3)*64, else W_tgt.
__global__ __launch_bounds__(256) void k1_proj(const float* __restrict__ x,
                                               const float* __restrict__ Wsrc,
                                               const float* __restrict__ Wtgt,
                                               double* __restrict__ ws) {
    __shared__ float xs[32 * 68];   // xs[k][m]
    __shared__ float wsh[32 * 68];  // ws[k][c]
    const int t = threadIdx.x;
    const int bx = blockIdx.x;
    const int by = blockIdx.y;
    const int col0 = (by & 3) * 64;
    const float* __restrict__ W = (by < 4) ? Wsrc : Wtgt;
    double* __restrict__ outp = ws + ((by < 4) ? 0 : 2097152);

    double acc[4][4];
#pragma unroll
    for (int i = 0; i < 4; ++i)
#pragma unroll
        for (int j = 0; j < 4; ++j) acc[i][j] = 0.0;

    const int m_loc = (t & 15) * 4;
    const int c_loc = (t >> 4) * 4;

    for (int kt = 0; kt < 8; ++kt) {
        __syncthreads();
#pragma unroll
        for (int it = 0; it < 2; ++it) {
            int f4 = t + 256 * it;
            int m = f4 >> 3, k4 = f4 & 7;
            float4 v = *reinterpret_cast<const float4*>(&x[(bx * 64 + m) * 256 + kt * 32 + 4 * k4]);
            xs[(4 * k4 + 0) * 68 + m] = v.x;
            xs[(4 * k4 + 1) * 68 + m] = v.y;
            xs[(4 * k4 + 2) * 68 + m] = v.z;
            xs[(4 * k4 + 3) * 68 + m] = v.w;
        }
#pragma unroll
        for (int it = 0; it < 2; ++it) {
            int f4 = t + 256 * it;
            int k = f4 >> 4, c4 = f4 & 15;
            *reinterpret_cast<float4*>(&wsh[k * 68 + 4 * c4]) =
                *reinterpret_cast<const float4*>(&W[(kt * 32 + k) * 256 + col0 + 4 * c4]);
        }
        __syncthreads();
#pragma unroll
        for (int kk = 0; kk < 32; ++kk) {
            float4 a = *reinterpret_cast<const float4*>(&xs[kk * 68 + m_loc]);
            float4 b = *reinterpret_cast<const float4*>(&wsh[kk * 68 + c_loc]);
            double ad[4] = {a.x, a.y, a.z, a.w};
            double bd[4] = {b.x, b.y, b.z, b.w};
#pragma unroll
            for (int i = 0; i < 4; ++i)
#pragma unroll
                for (int j = 0; j < 4; ++j) acc[i][j] += ad[i] * bd[j];
        }
    }
    const int h = by & 3;
#pragma unroll
    for (int i = 0; i < 4; ++i) {
        int m = bx * 64 + m_loc + i;
        int b = m >> 10, n = m & 1023;
        size_t base = ((size_t)((b * 4 + h) * 1024 + n)) * 64 + c_loc;
        double2 v01, v23;
        v01.x = acc[i][0]; v01.y = acc[i][1];
        v23.x = acc[i][2]; v23.y = acc[i][3];
        *reinterpret_cast<double2*>(&outp[base]) = v01;
        *reinterpret_cast<double2*>(&outp[base + 2]) = v23;
    }
}

// ---------------- K2: f64 adj GEMM + exact top-k + f32 gelu output ----------------
// grid 2048: bh = bx>>6, itile = bx&63 -> 16 rows. 256 thr = 4 waves, wave owns 4 rows.
// vals[r][c]: row r0+r, col = lane + 64*c. c = b*8+m (b: 512-col batch, m: col sub).
__global__ __launch_bounds__(256) void k2_fused(const double* __restrict__ srcT,
                                                const double* __restrict__ tgtT,
                                                float* __restrict__ out) {
    __shared__ double2 tgt_s[8 * 512];      // 64 KB, slot = d2l*512 + (js ^ d2l)
    __shared__ unsigned hist[4][256];       // 4 KB, per-wave
    __shared__ unsigned long long keyList[4][16];
    __shared__ unsigned jList[4][16];
    __shared__ unsigned listCnt[4];

    const int t = threadIdx.x;
    const int lane = t & 63;
    const int wv = t >> 6;
    const int bh = blockIdx.x >> 6;
    const int itile = blockIdx.x & 63;
    const int row0 = itile * 16;
    const int r0 = 4 * wv;
    const size_t tgtBase = (size_t)bh * 65536;                    // 1024*64
    const size_t srcRow = ((size_t)bh * 1024 + row0 + r0) * 64;   // wave's first row

    double vals[4][16];
#pragma unroll
    for (int r = 0; r < 4; ++r)
#pragma unroll
        for (int c = 0; c < 16; ++c) vals[r][c] = 0.0;

    const int s_r = lane >> 4;    // src row held by this lane (0..3)
    const int s_dl = lane & 15;   // src d-offset within subtile
    const int st_d2l = t & 7;     // staging: d-pair index
    const int st_j = t >> 3;      // staging: col base

#pragma unroll
    for (int b = 0; b < 2; ++b) {
#pragma unroll 1
        for (int dsub = 0; dsub < 4; ++dsub) {
            // wave's 4 src rows x 16 d (this subtile) live in 1 f64/lane
            double sreg = srcT[srcRow + (size_t)s_r * 64 + dsub * 16 + s_dl];

            __syncthreads();  // previous stage fully consumed
            // stage tgt tile: 512 cols x 16 d, swizzled
#pragma unroll
            for (int it = 0; it < 16; ++it) {
                int js = st_j + 32 * it;
                double2 v = *reinterpret_cast<const double2*>(
                    &tgtT[tgtBase + (size_t)(b * 512 + js) * 64 + dsub * 16 + 2 * st_d2l]);
                tgt_s[st_d2l * 512 + (js ^ st_d2l)] = v;
            }
            __syncthreads();

#pragma unroll
            for (int d2l = 0; d2l < 8; ++d2l) {
                double s0[4], s1[4];
#pragma unroll
                for (int r = 0; r < 4; ++r) {
                    s0[r] = __shfl(sreg, (r << 4) | (2 * d2l), 64);      // v_readlane
                    s1[r] = __shfl(sreg, (r << 4) | (2 * d2l + 1), 64);
                }
#pragma unroll
                for (int m = 0; m < 8; ++m) {
                    double2 bv = tgt_s[d2l * 512 + ((lane + 64 * m) ^ d2l)];
#pragma unroll
                    for (int r = 0; r < 4; ++r)
                        vals[r][b * 8 + m] += s0[r] * bv.x + s1[r] * bv.y;
                }
            }
        }
    }

    // ---------------- per-wave exact top-k select + masked gelu write ----------------
    const size_t outBase = ((size_t)bh * 1024 + row0 + r0) * 1024;

#pragma unroll
    for (int ri = 0; ri < 4; ++ri) {
        unsigned ul[16];
#pragma unroll
        for (int m = 0; m < 16; ++m) ul[m] = lkey(vals[ri][m]);

        unsigned prefA = 0u, maskA = 0u, rk = KSEL;
        bool done = false;

#pragma unroll 1
        for (int p = 3; p >= 0; --p) {
            const int sh = 8 * p;
            *reinterpret_cast<uint4*>(&hist[wv][4 * lane]) = make_uint4(0u, 0u, 0u, 0u);
            asm volatile("s_waitcnt lgkmcnt(0)" ::: "memory");
#pragma unroll
            for (int m = 0; m < 16; ++m) {
                if ((ul[m] & maskA) == prefA)
                    atomicAdd(&hist[wv][(ul[m] >> sh) & 255u], 1u);
            }
            asm volatile("s_waitcnt lgkmcnt(0)" ::: "memory");
            unsigned h0 = hist[wv][4 * lane + 0], h1 = hist[wv][4 * lane + 1];
            unsigned h2 = hist[wv][4 * lane + 2], h3 = hist[wv][4 * lane + 3];
            unsigned S = h0 + h1 + h2 + h3;
            unsigned inc = S;  // suffix-inclusive sum over lanes >= lane
#pragma unroll
            for (int off = 1; off < 64; off <<= 1) {
                unsigned o = __shfl_down(inc, off, 64);
                inc = (lane + off < 64) ? (inc + o) : inc;
            }
            unsigned above = inc - S;
            bool found = (above < rk) && (rk <= inc);
            unsigned long long bal = __ballot(found);
            int L = __ffsll(bal) - 1;
            unsigned hh[4];
            hh[0] = __shfl(h0, L, 64);
            hh[1] = __shfl(h1, L, 64);
            hh[2] = __shfl(h2, L, 64);
            hh[3] = __shfl(h3, L, 64);
            unsigned cum = __shfl(above, L, 64);
            int bsel = -1;
            unsigned cnt = 0;
#pragma unroll
            for (int q = 3; q >= 0; --q) {
                if (bsel < 0) {
                    if (rk <= cum + hh[q]) {
                        bsel = q;
                        cnt = hh[q];
                        rk = rk - cum;
                    } else {
                        cum += hh[q];
                    }
                }
            }
            prefA |= (unsigned)(4 * L + bsel) << sh;
            maskA |= 0xFFu << sh;
            if (rk == cnt) { done = true; break; }  // bucket fully selected
        }

        unsigned g = 0;
        if (!done) {
            // rare: boundary class has a 32-bit-key tie; rank tied values by exact f64
            if (lane == 0) listCnt[wv] = 0u;
            asm volatile("s_waitcnt lgkmcnt(0)" ::: "memory");
#pragma unroll
            for (int m = 0; m < 16; ++m) {
                if (ul[m] == prefA) {
                    unsigned idx = atomicAdd(&listCnt[wv], 1u);
                    if (idx < 16u) {
                        keyList[wv][idx] = d2key(vals[ri][m]);
                        jList[wv][idx] = (unsigned)(lane + 64 * m);
                    }
                }
            }
            asm volatile("s_waitcnt lgkmcnt(0)" ::: "memory");
            g = listCnt[wv];
            if (g > 16u) g = 16u;
        }

        const size_t rowBase = outBase + (size_t)ri * 1024;
#pragma unroll
        for (int m = 0; m < 16; ++m) {
            bool sel;
            if (done) {
                sel = ((ul[m] & maskA) >= prefA);
            } else if (ul[m] > prefA) {
                sel = true;
            } else if (ul[m] < prefA) {
                sel = false;
            } else {
                unsigned long long myk = d2key(vals[ri][m]);
                unsigned myj = (unsigned)(lane + 64 * m);
                unsigned rnk = 0;
                for (unsigned i = 0; i < g; ++i) {
                    unsigned long long ki = keyList[wv][i];
                    rnk += (ki > myk || (ki == myk && jList[wv][i] < myj)) ? 1u : 0u;
                }
                sel = (rnk < rk);
            }
            float gv = sel ? gelu_f32((float)vals[ri][m]) : 0.0f;
            out[rowBase + (unsigned)(lane + 64 * m)] = gv;
        }
    }
}

extern "C" void kernel_launch(void* const* d_in, const int* in_sizes, int n_in,
                              void* d_out, int out_size, void* d_ws, size_t ws_size,
                              hipStream_t stream) {
    const float* x = (const float*)d_in[0];
    const float* Wsrc = (const float*)d_in[1];
    const float* Wtgt = (const float*)d_in[2];
    float* out = (float*)d_out;
    double* ws = (double*)d_ws;  // 32MB: src_t f64 (16MB) + tgt_t f64 (16MB)

    dim3 g1(128, 8);
    k1_proj<<<g1, 256, 0, stream>>>(x, Wsrc, Wtgt, ws);
    k2_fused<<<2048, 256, 0, stream>>>(ws, ws + 2097152, out);
}